// Round 4
// baseline (234.817 us; speedup 1.0000x reference)
//
#include <hip/hip_runtime.h>
#include <stdint.h>

#define LOG2E 1.44269504088896340736f

using bf16x8 = __attribute__((ext_vector_type(8))) short;  // 8 bf16 (4 VGPRs)
using f32x4  = __attribute__((ext_vector_type(4))) float;

__device__ __forceinline__ ushort f2bf(float f) {
  union { float f; uint32_t u; } v; v.f = f;
  uint32_t u = v.u;
  u += 0x7FFFu + ((u >> 16) & 1u);   // RNE
  return (ushort)(u >> 16);
}
__device__ __forceinline__ float bf2f(ushort b) {
  union { uint32_t u; float f; } v; v.u = ((uint32_t)b) << 16;
  return v.f;
}

__device__ __forceinline__ void load_lds16(const void* g, void* l) {
  __builtin_amdgcn_global_load_lds(
      (const __attribute__((address_space(1))) void*)g,
      (__attribute__((address_space(3))) void*)l, 16, 0, 0);
}

// out[row] = dot(mat[row, 0:512], vec[0:512]); 4 rows per 256-thread block
__global__ void rowdot(const float* __restrict__ mat, const float* __restrict__ vec,
                       float* __restrict__ out) {
  int w = threadIdx.x >> 6, l = threadIdx.x & 63;
  int row = blockIdx.x * 4 + w;
  const float4* mp = (const float4*)(mat + row * 512 + l * 8);
  const float4* vp = (const float4*)(vec + l * 8);
  float4 a0 = mp[0], a1 = mp[1];
  float4 b0 = vp[0], b1 = vp[1];
  float d = a0.x * b0.x + a0.y * b0.y + a0.z * b0.z + a0.w * b0.w
          + a1.x * b1.x + a1.y * b1.y + a1.z * b1.z + a1.w * b1.w;
#pragma unroll
  for (int o = 32; o > 0; o >>= 1) d += __shfl_xor(d, o, 64);
  if (l == 0) out[row] = d;
}

__global__ void reduce_max(const float* __restrict__ v, float* __restrict__ outmax) {
  __shared__ float red[4];
  int t = threadIdx.x;
  float m = -3.0e38f;
  for (int j = t; j < 8192; j += 256) m = fmaxf(m, v[j]);
#pragma unroll
  for (int o = 32; o > 0; o >>= 1) m = fmaxf(m, __shfl_xor(m, o, 64));
  if ((t & 63) == 0) red[t >> 6] = m;
  __syncthreads();
  if (t == 0) outmax[0] = fmaxf(fmaxf(red[0], red[1]), fmaxf(red[2], red[3]));
}

__global__ void cvt4_bf16(const float* __restrict__ in, ushort* __restrict__ out) {
  int idx = blockIdx.x * 256 + threadIdx.x;
  float4 v = ((const float4*)in)[idx];
  ushort4 o; o.x = f2bf(v.x); o.y = f2bf(v.y); o.z = f2bf(v.z); o.w = f2bf(v.w);
  ((ushort4*)out)[idx] = o;
}

// wT_bf[f][c] = bf16(weight[c][f]); 512x512
__global__ void transpose_w(const float* __restrict__ w, ushort* __restrict__ wT) {
  __shared__ float tile[32][33];
  int t = threadIdx.x; int tx = t & 31, ty = t >> 5;
  int cb = (blockIdx.x & 15) * 32, fb = (blockIdx.x >> 4) * 32;
#pragma unroll
  for (int k = 0; k < 4; ++k) tile[ty + k * 8][tx] = w[(cb + ty + k * 8) * 512 + fb + tx];
  __syncthreads();
#pragma unroll
  for (int k = 0; k < 4; ++k) wT[(fb + ty + k * 8) * 512 + cb + tx] = f2bf(tile[tx][ty + k * 8]);
}

// WhmT[f][j] = sum_c neigh_bf[j][c] * wT_bf[f][c]   (bf16 out, transposed store)
__global__ __launch_bounds__(256, 4) void gemm_whmT(const ushort* __restrict__ A,
                                                    const ushort* __restrict__ B,
                                                    ushort* __restrict__ WhmT) {
  __shared__ ushort At[128 * 32];
  __shared__ ushort Bt2[128 * 32];
  int t = threadIdx.x;
  int j0 = (blockIdx.x >> 2) * 128, f0 = (blockIdx.x & 3) * 128;
  int w = t >> 6, l = t & 63, wr = w >> 1, wc = w & 1;
  f32x4 acc[4][4] = {};
  for (int it = 0; it < 16; ++it) {
    int k0 = it * 32;
#pragma unroll
    for (int c = 0; c < 2; ++c) {
      int u = c * 256 + t; int rr = u >> 2, p = u & 3;
      int sg = p ^ ((rr >> 1) & 3);
      load_lds16(A + (j0 + rr) * 512 + k0 + sg * 8, At + (c * 256 + (t & ~63)) * 8);
      load_lds16(B + (f0 + rr) * 512 + k0 + sg * 8, Bt2 + (c * 256 + (t & ~63)) * 8);
    }
    __syncthreads();
    bf16x8 af[4], bfr[4];
#pragma unroll
    for (int m = 0; m < 4; ++m) {
      int rr = wr * 64 + m * 16 + (l & 15);
      int q = (l >> 4) ^ ((rr >> 1) & 3);
      af[m] = *(const bf16x8*)(At + rr * 32 + q * 8);
    }
#pragma unroll
    for (int n = 0; n < 4; ++n) {
      int rb = wc * 64 + n * 16 + (l & 15);
      int q = (l >> 4) ^ ((rb >> 1) & 3);
      bfr[n] = *(const bf16x8*)(Bt2 + rb * 32 + q * 8);
    }
#pragma unroll
    for (int m = 0; m < 4; ++m)
#pragma unroll
      for (int n = 0; n < 4; ++n)
        acc[m][n] = __builtin_amdgcn_mfma_f32_16x16x32_bf16(af[m], bfr[n], acc[m][n], 0, 0, 0);
    __syncthreads();
  }
#pragma unroll
  for (int m = 0; m < 4; ++m)
#pragma unroll
    for (int n = 0; n < 4; ++n) {
      int j = j0 + wr * 64 + m * 16 + (l >> 4) * 4;
      int f = f0 + wc * 64 + n * 16 + (l & 15);
      ushort4 o;
      o.x = f2bf(acc[m][n][0]); o.y = f2bf(acc[m][n][1]);
      o.z = f2bf(acc[m][n][2]); o.w = f2bf(acc[m][n][3]);
      *(ushort4*)(WhmT + f * 8192 + j) = o;
    }
}

// ---------------------------------------------------------------------------
// Main fused kernel v4: BM=64, BN=512, BK=32, Ksplit=8 -> grid 512 (2 blk/CU).
// Coalesced global_load_lds B staging (dbuf), Pt dbuf, counted vmcnt(8)
// pipeline (no drains in loop), pair prefetch depth-2, setprio on MFMA.
//   num[s][i][f] (bf16) = sum_{j in ksplit s} P[i][j]*Whm[j][f]; den[s][i]=sum P
//   P[i][j] = mask ? exp(lrelu(sn[i]+sm[j]) - m_i) : 0, m_i = lrelu(sn[i]+Smax)
// ---------------------------------------------------------------------------
__global__ __launch_bounds__(512, 4) void attn_main(
    const ushort* __restrict__ WhmT, const int* __restrict__ mask,
    const float* __restrict__ s_n, const float* __restrict__ s_m,
    const float* __restrict__ smaxp, ushort* __restrict__ num, float* __restrict__ den) {
  __shared__ ushort Bt[2][512 * 32];  // 2 x 32 KB, xor-swizzled [f][32j]
  __shared__ ushort Pt[2][64 * 32];   // 2 x 4 KB, xor-swizzled [i][32j]
  int t = threadIdx.x;
  int bid = blockIdx.x;
  int s = bid & 7;           // ksplit == XCD id under round-robin dispatch
  int rblk = bid >> 3;       // 0..63
  int i0 = rblk * 64;
  int kb = s * 1024;
  int w = t >> 6, l = t & 63, l15 = l & 15;
  int i_loc = t >> 3, jt = t & 7;

  float sn = s_n[i0 + i_loc];
  float smx = smaxp[0];
  float mz = sn + smx;
  float m_i = mz > 0.f ? mz : 0.2f * mz;
  float miL = m_i * LOG2E;
  float dacc = 0.f;
  f32x4 acc[4][4] = {};

  // P write addrs (4 bf16 per thread, xor-swizzled 16B groups)
  int psP = (jt >> 1) ^ ((i_loc >> 1) & 3);
  ushort* pw0 = &Pt[0][0] + i_loc * 32 + psP * 8 + (jt & 1) * 4;
  ushort* pw1 = &Pt[1][0] + i_loc * 32 + psP * 8 + (jt & 1) * 4;
  // frag read bases (swizzle group independent of m/n since 16|row steps)
  int qA = (l >> 4) ^ ((l15 >> 1) & 3);
  const ushort* pa0 = &Pt[0][0] + l15 * 32 + qA * 8;
  const ushort* pa1 = &Pt[1][0] + l15 * 32 + qA * 8;
  const ushort* pb0 = &Bt[0][0] + (w * 64 + l15) * 32 + qA * 8;
  const ushort* pb1 = &Bt[1][0] + (w * 64 + l15) * 32 + qA * 8;

  const int* mrow = mask + (size_t)(i0 + i_loc) * 8192 + kb + jt * 4;
  const float* sptr = s_m + kb + jt * 4;

#define STAGE_B(BUF_, T_)                                                     \
  {                                                                           \
    int k0_ = kb + (T_) * 32;                                                 \
    ushort* bb_ = BUF_;                                                       \
    _Pragma("unroll") for (int c = 0; c < 4; ++c) {                           \
      int u_ = c * 512 + t; int rr_ = u_ >> 2, p_ = u_ & 3;                   \
      int sg_ = p_ ^ ((rr_ >> 1) & 3);                                        \
      load_lds16(WhmT + rr_ * 8192 + k0_ + sg_ * 8,                           \
                 bb_ + (c * 512 + (t & ~63)) * 8);                            \
    }                                                                         \
  }

#define P_COMP(mkv, svv, pdst)                                                \
  {                                                                           \
    float z0 = sn + (svv).x, z1 = sn + (svv).y;                               \
    float z2 = sn + (svv).z, z3 = sn + (svv).w;                               \
    float e0 = (z0 > 0.f ? z0 : 0.2f * z0) * LOG2E - miL;                     \
    float e1 = (z1 > 0.f ? z1 : 0.2f * z1) * LOG2E - miL;                     \
    float e2 = (z2 > 0.f ? z2 : 0.2f * z2) * LOG2E - miL;                     \
    float e3 = (z3 > 0.f ? z3 : 0.2f * z3) * LOG2E - miL;                     \
    float p0 = (mkv).x > 0 ? exp2f(e0) : 0.f;                                 \
    float p1 = (mkv).y > 0 ? exp2f(e1) : 0.f;                                 \
    float p2 = (mkv).z > 0 ? exp2f(e2) : 0.f;                                 \
    float p3 = (mkv).w > 0 ? exp2f(e3) : 0.f;                                 \
    ushort4 pv;                                                               \
    pv.x = f2bf(p0); pv.y = f2bf(p1); pv.z = f2bf(p2); pv.w = f2bf(p3);       \
    dacc += bf2f(pv.x) + bf2f(pv.y) + bf2f(pv.z) + bf2f(pv.w);                \
    *(ushort4*)(pdst) = pv;                                                   \
  }

  // body(it): [stage B(it+1)] [P(it+1)->Pt, reload pair(it+3)] [lgkm+bar]
  // [vmcnt(VMC)] [ds_read frags from buf CUR] [16 MFMA] [bar]
#define BODY(IT_, PA_, PB_, PW_, MKV_, SVV_, NXTB_, DO_P, DO_STAGE, VMC_)     \
  {                                                                           \
    if (DO_STAGE) { STAGE_B(NXTB_, (IT_) + 1); }                              \
    __builtin_amdgcn_sched_barrier(0);                                        \
    if (DO_P) { P_COMP(MKV_, SVV_, PW_); }                                    \
    if (DO_STAGE) {                                                           \
      int kM_ = (((IT_) + 3) & 31) * 32;                                      \
      MKV_ = *(const int4*)(mrow + kM_);                                      \
      SVV_ = *(const float4*)(sptr + kM_);                                    \
    }                                                                         \
    __builtin_amdgcn_sched_barrier(0);                                        \
    asm volatile("s_waitcnt lgkmcnt(0)\n\ts_barrier" ::: "memory");           \
    asm volatile("s_waitcnt vmcnt(" #VMC_ ")" ::: "memory");                  \
    bf16x8 af[4], bfr[4];                                                     \
    _Pragma("unroll") for (int m = 0; m < 4; ++m)                             \
      af[m] = *(const bf16x8*)(PA_ + m * 512);                                \
    _Pragma("unroll") for (int n = 0; n < 4; ++n)                             \
      bfr[n] = *(const bf16x8*)(PB_ + n * 512);                               \
    __builtin_amdgcn_s_setprio(1);                                            \
    _Pragma("unroll") for (int m = 0; m < 4; ++m)                             \
      _Pragma("unroll") for (int n = 0; n < 4; ++n)                           \
        acc[m][n] = __builtin_amdgcn_mfma_f32_16x16x32_bf16(af[m], bfr[n],    \
                                                            acc[m][n], 0, 0, 0); \
    __builtin_amdgcn_s_setprio(0);                                            \
    asm volatile("s_barrier" ::: "memory");                                   \
  }

  // ---- prologue ----
  STAGE_B(&Bt[0][0], 0);
  __builtin_amdgcn_sched_barrier(0);
  {
    int4 mk0 = *(const int4*)(mrow);
    float4 sv0 = *(const float4*)(sptr);
    P_COMP(mk0, sv0, pw0);
  }
  int4 mkA = *(const int4*)(mrow + 32);
  float4 svA = *(const float4*)(sptr + 32);
  int4 mkB = *(const int4*)(mrow + 64);
  float4 svB = *(const float4*)(sptr + 64);
  __builtin_amdgcn_sched_barrier(0);
  asm volatile("s_waitcnt lgkmcnt(0)\n\ts_barrier" ::: "memory");

  // ---- main loop: 32 K-steps, unrolled by 2 ----
  for (int it2 = 0; it2 < 15; ++it2) {
    int it = it2 * 2;
    BODY(it,     pa0, pb0, pw1, mkA, svA, &Bt[1][0], true, true, 8);
    BODY(it + 1, pa1, pb1, pw0, mkB, svB, &Bt[0][0], true, true, 8);
  }
  BODY(30, pa0, pb0, pw1, mkA, svA, &Bt[1][0], true, true, 8);
  BODY(31, pa1, pb1, pw0, mkB, svB, &Bt[0][0], false, false, 2);

  // ---- denominator: 8 threads per row (within one wave) ----
  dacc += __shfl_xor(dacc, 4, 64);
  dacc += __shfl_xor(dacc, 2, 64);
  dacc += __shfl_xor(dacc, 1, 64);
  if ((t & 7) == 0) den[s * 4096 + i0 + i_loc] = dacc;
  // ---- partial numerator write (bf16) ----
#pragma unroll
  for (int m = 0; m < 4; ++m)
#pragma unroll
    for (int n = 0; n < 4; ++n) {
      int i = i0 + m * 16 + (l >> 4) * 4;
      int f = w * 64 + n * 16 + l15;
      ushort* dst = num + ((size_t)(s * 4096) + i) * 512 + f;
      dst[0]        = f2bf(acc[m][n][0]);
      dst[512]      = f2bf(acc[m][n][1]);
      dst[2 * 512]  = f2bf(acc[m][n][2]);
      dst[3 * 512]  = f2bf(acc[m][n][3]);
    }
#undef BODY
#undef P_COMP
#undef STAGE_B
}

// out[i][f] = (sum_s num[s][i][f]) / (sum_s den[s][i]);  num is bf16
__global__ void reduce_out(const ushort* __restrict__ num, const float* __restrict__ den,
                           float* __restrict__ out) {
  int idx = blockIdx.x * 256 + threadIdx.x;  // 524288 threads
  int i = idx >> 7, f4 = (idx & 127) * 4;
  float s0 = 0.f, s1 = 0.f, s2 = 0.f, s3 = 0.f;
#pragma unroll
  for (int s = 0; s < 8; ++s) {
    ushort4 v = *(const ushort4*)(num + ((size_t)(s * 4096) + i) * 512 + f4);
    s0 += bf2f(v.x); s1 += bf2f(v.y); s2 += bf2f(v.z); s3 += bf2f(v.w);
  }
  float dn = 0.f;
#pragma unroll
  for (int s = 0; s < 8; ++s) dn += den[s * 4096 + i];
  float inv = 1.f / dn;
  float4 o; o.x = s0 * inv; o.y = s1 * inv; o.z = s2 * inv; o.w = s3 * inv;
  *(float4*)(out + (size_t)i * 512 + f4) = o;
}

extern "C" void kernel_launch(void* const* d_in, const int* in_sizes, int n_in,
                              void* d_out, int out_size, void* d_ws, size_t ws_size,
                              hipStream_t stream) {
  const float* node   = (const float*)d_in[0];
  const float* neigh  = (const float*)d_in[1];
  const float* weight = (const float*)d_in[2];
  const float* att    = (const float*)d_in[3];
  const int*   mask   = (const int*)d_in[4];
  float* out = (float*)d_out;

  char* ws = (char*)d_ws;
  float* w_a1 = (float*)ws;            // 512
  float* w_a2 = w_a1 + 512;            // 512
  float* s_n  = w_a2 + 512;            // 4096
  float* s_m  = s_n + 4096;            // 8192
  float* smax = s_m + 8192;            // 1
  ushort* neigh_bf = (ushort*)(ws + 64 * 1024);    // 8 MB
  ushort* wT_bf    = neigh_bf + 8192 * 512;        // 0.5 MB
  ushort* WhmT     = wT_bf + 512 * 512;            // 8 MB
  ushort* num      = WhmT + 512 * 8192;            // 32 MB (bf16, 8 slices)
  float*  den      = (float*)(num + 8 * 4096 * 512);  // 128 KB

  rowdot<<<128, 256, 0, stream>>>(weight, att, w_a1);
  rowdot<<<128, 256, 0, stream>>>(weight, att + 512, w_a2);
  rowdot<<<1024, 256, 0, stream>>>(node, w_a1, s_n);
  rowdot<<<2048, 256, 0, stream>>>(neigh, w_a2, s_m);
  reduce_max<<<1, 256, 0, stream>>>(s_m, smax);
  cvt4_bf16<<<4096, 256, 0, stream>>>(neigh, neigh_bf);
  transpose_w<<<256, 256, 0, stream>>>(weight, wT_bf);
  gemm_whmT<<<256, 256, 0, stream>>>(neigh_bf, wT_bf, WhmT);
  attn_main<<<512, 512, 0, stream>>>(WhmT, mask, s_n, s_m, smax, num, den);
  reduce_out<<<2048, 256, 0, stream>>>(num, den, out);
}

// Round 5
// 210.913 us; speedup vs baseline: 1.1133x; 1.1133x over previous
//
#include <hip/hip_runtime.h>
#include <stdint.h>

#define LOG2E 1.44269504088896340736f

using bf16x8 = __attribute__((ext_vector_type(8))) short;  // 8 bf16 (4 VGPRs)
using f32x4  = __attribute__((ext_vector_type(4))) float;

__device__ __forceinline__ ushort f2bf(float f) {
  union { float f; uint32_t u; } v; v.f = f;
  uint32_t u = v.u;
  u += 0x7FFFu + ((u >> 16) & 1u);   // RNE
  return (ushort)(u >> 16);
}
__device__ __forceinline__ float bf2f(ushort b) {
  union { uint32_t u; float f; } v; v.u = ((uint32_t)b) << 16;
  return v.f;
}

__device__ __forceinline__ void load_lds16(const void* g, void* l) {
  __builtin_amdgcn_global_load_lds(
      (const __attribute__((address_space(1))) void*)g,
      (__attribute__((address_space(3))) void*)l, 16, 0, 0);
}

// out[row] = dot(mat[row, 0:512], vec[0:512]); 4 rows per 256-thread block
__global__ void rowdot(const float* __restrict__ mat, const float* __restrict__ vec,
                       float* __restrict__ out) {
  int w = threadIdx.x >> 6, l = threadIdx.x & 63;
  int row = blockIdx.x * 4 + w;
  const float4* mp = (const float4*)(mat + row * 512 + l * 8);
  const float4* vp = (const float4*)(vec + l * 8);
  float4 a0 = mp[0], a1 = mp[1];
  float4 b0 = vp[0], b1 = vp[1];
  float d = a0.x * b0.x + a0.y * b0.y + a0.z * b0.z + a0.w * b0.w
          + a1.x * b1.x + a1.y * b1.y + a1.z * b1.z + a1.w * b1.w;
#pragma unroll
  for (int o = 32; o > 0; o >>= 1) d += __shfl_xor(d, o, 64);
  if (l == 0) out[row] = d;
}

__global__ void reduce_max(const float* __restrict__ v, float* __restrict__ outmax) {
  __shared__ float red[4];
  int t = threadIdx.x;
  float m = -3.0e38f;
  for (int j = t; j < 8192; j += 256) m = fmaxf(m, v[j]);
#pragma unroll
  for (int o = 32; o > 0; o >>= 1) m = fmaxf(m, __shfl_xor(m, o, 64));
  if ((t & 63) == 0) red[t >> 6] = m;
  __syncthreads();
  if (t == 0) outmax[0] = fmaxf(fmaxf(red[0], red[1]), fmaxf(red[2], red[3]));
}

__global__ void cvt4_bf16(const float* __restrict__ in, ushort* __restrict__ out) {
  int idx = blockIdx.x * 256 + threadIdx.x;
  float4 v = ((const float4*)in)[idx];
  ushort4 o; o.x = f2bf(v.x); o.y = f2bf(v.y); o.z = f2bf(v.z); o.w = f2bf(v.w);
  ((ushort4*)out)[idx] = o;
}

// wT_bf[f][c] = bf16(weight[c][f]); 512x512
__global__ void transpose_w(const float* __restrict__ w, ushort* __restrict__ wT) {
  __shared__ float tile[32][33];
  int t = threadIdx.x; int tx = t & 31, ty = t >> 5;
  int cb = (blockIdx.x & 15) * 32, fb = (blockIdx.x >> 4) * 32;
#pragma unroll
  for (int k = 0; k < 4; ++k) tile[ty + k * 8][tx] = w[(cb + ty + k * 8) * 512 + fb + tx];
  __syncthreads();
#pragma unroll
  for (int k = 0; k < 4; ++k) wT[(fb + ty + k * 8) * 512 + cb + tx] = f2bf(tile[tx][ty + k * 8]);
}

// WhmT[f][j] = sum_c neigh_bf[j][c] * wT_bf[f][c]   (bf16 out, transposed store)
__global__ __launch_bounds__(256, 4) void gemm_whmT(const ushort* __restrict__ A,
                                                    const ushort* __restrict__ B,
                                                    ushort* __restrict__ WhmT) {
  __shared__ ushort At[128 * 32];
  __shared__ ushort Bt2[128 * 32];
  int t = threadIdx.x;
  int j0 = (blockIdx.x >> 2) * 128, f0 = (blockIdx.x & 3) * 128;
  int w = t >> 6, l = t & 63, wr = w >> 1, wc = w & 1;
  f32x4 acc[4][4] = {};
  for (int it = 0; it < 16; ++it) {
    int k0 = it * 32;
#pragma unroll
    for (int c = 0; c < 2; ++c) {
      int u = c * 256 + t; int rr = u >> 2, p = u & 3;
      int sg = p ^ ((rr >> 1) & 3);
      load_lds16(A + (j0 + rr) * 512 + k0 + sg * 8, At + (c * 256 + (t & ~63)) * 8);
      load_lds16(B + (f0 + rr) * 512 + k0 + sg * 8, Bt2 + (c * 256 + (t & ~63)) * 8);
    }
    __syncthreads();
    bf16x8 af[4], bfr[4];
#pragma unroll
    for (int m = 0; m < 4; ++m) {
      int rr = wr * 64 + m * 16 + (l & 15);
      int q = (l >> 4) ^ ((rr >> 1) & 3);
      af[m] = *(const bf16x8*)(At + rr * 32 + q * 8);
    }
#pragma unroll
    for (int n = 0; n < 4; ++n) {
      int rb = wc * 64 + n * 16 + (l & 15);
      int q = (l >> 4) ^ ((rb >> 1) & 3);
      bfr[n] = *(const bf16x8*)(Bt2 + rb * 32 + q * 8);
    }
#pragma unroll
    for (int m = 0; m < 4; ++m)
#pragma unroll
      for (int n = 0; n < 4; ++n)
        acc[m][n] = __builtin_amdgcn_mfma_f32_16x16x32_bf16(af[m], bfr[n], acc[m][n], 0, 0, 0);
    __syncthreads();
  }
#pragma unroll
  for (int m = 0; m < 4; ++m)
#pragma unroll
    for (int n = 0; n < 4; ++n) {
      int j = j0 + wr * 64 + m * 16 + (l >> 4) * 4;
      int f = f0 + wc * 64 + n * 16 + (l & 15);
      ushort4 o;
      o.x = f2bf(acc[m][n][0]); o.y = f2bf(acc[m][n][1]);
      o.z = f2bf(acc[m][n][2]); o.w = f2bf(acc[m][n][3]);
      *(ushort4*)(WhmT + f * 8192 + j) = o;
    }
}

// ---------------------------------------------------------------------------
// Main fused kernel v5: BM=64, BN=512, BK=32, Ksplit=8 -> grid 512 (2 blk/CU).
// Coalesced global_load_lds B staging (dbuf), Pt dbuf, counted vmcnt(8)
// pipeline, setprio on MFMA. Numerator stored PACKED:
//   num[s][i>>2][f][i&3] (bf16) -> acc's 4 consecutive rows = one ushort4,
//   lanes 0-15 cover 16 consecutive f -> 128B full-line coalesced stores.
// ---------------------------------------------------------------------------
__global__ __launch_bounds__(512, 4) void attn_main(
    const ushort* __restrict__ WhmT, const int* __restrict__ mask,
    const float* __restrict__ s_n, const float* __restrict__ s_m,
    const float* __restrict__ smaxp, ushort* __restrict__ num, float* __restrict__ den) {
  __shared__ ushort Bt[2][512 * 32];  // 2 x 32 KB, xor-swizzled [f][32j]
  __shared__ ushort Pt[2][64 * 32];   // 2 x 4 KB, xor-swizzled [i][32j]
  int t = threadIdx.x;
  int bid = blockIdx.x;
  int s = bid & 7;           // ksplit == XCD id under round-robin dispatch
  int rblk = bid >> 3;       // 0..63
  int i0 = rblk * 64;
  int kb = s * 1024;
  int w = t >> 6, l = t & 63, l15 = l & 15;
  int i_loc = t >> 3, jt = t & 7;

  float sn = s_n[i0 + i_loc];
  float smx = smaxp[0];
  float mz = sn + smx;
  float m_i = mz > 0.f ? mz : 0.2f * mz;
  float miL = m_i * LOG2E;
  float dacc = 0.f;
  f32x4 acc[4][4] = {};

  // P write addrs (4 bf16 per thread, xor-swizzled 16B groups)
  int psP = (jt >> 1) ^ ((i_loc >> 1) & 3);
  ushort* pw0 = &Pt[0][0] + i_loc * 32 + psP * 8 + (jt & 1) * 4;
  ushort* pw1 = &Pt[1][0] + i_loc * 32 + psP * 8 + (jt & 1) * 4;
  // frag read bases (swizzle group independent of m/n since 16|row steps)
  int qA = (l >> 4) ^ ((l15 >> 1) & 3);
  const ushort* pa0 = &Pt[0][0] + l15 * 32 + qA * 8;
  const ushort* pa1 = &Pt[1][0] + l15 * 32 + qA * 8;
  const ushort* pb0 = &Bt[0][0] + (w * 64 + l15) * 32 + qA * 8;
  const ushort* pb1 = &Bt[1][0] + (w * 64 + l15) * 32 + qA * 8;

  const int* mrow = mask + (size_t)(i0 + i_loc) * 8192 + kb + jt * 4;
  const float* sptr = s_m + kb + jt * 4;

#define STAGE_B(BUF_, T_)                                                     \
  {                                                                           \
    int k0_ = kb + (T_) * 32;                                                 \
    ushort* bb_ = BUF_;                                                       \
    _Pragma("unroll") for (int c = 0; c < 4; ++c) {                           \
      int u_ = c * 512 + t; int rr_ = u_ >> 2, p_ = u_ & 3;                   \
      int sg_ = p_ ^ ((rr_ >> 1) & 3);                                        \
      load_lds16(WhmT + rr_ * 8192 + k0_ + sg_ * 8,                           \
                 bb_ + (c * 512 + (t & ~63)) * 8);                            \
    }                                                                         \
  }

#define P_COMP(mkv, svv, pdst)                                                \
  {                                                                           \
    float z0 = sn + (svv).x, z1 = sn + (svv).y;                               \
    float z2 = sn + (svv).z, z3 = sn + (svv).w;                               \
    float e0 = (z0 > 0.f ? z0 : 0.2f * z0) * LOG2E - miL;                     \
    float e1 = (z1 > 0.f ? z1 : 0.2f * z1) * LOG2E - miL;                     \
    float e2 = (z2 > 0.f ? z2 : 0.2f * z2) * LOG2E - miL;                     \
    float e3 = (z3 > 0.f ? z3 : 0.2f * z3) * LOG2E - miL;                     \
    float p0 = (mkv).x > 0 ? exp2f(e0) : 0.f;                                 \
    float p1 = (mkv).y > 0 ? exp2f(e1) : 0.f;                                 \
    float p2 = (mkv).z > 0 ? exp2f(e2) : 0.f;                                 \
    float p3 = (mkv).w > 0 ? exp2f(e3) : 0.f;                                 \
    ushort4 pv;                                                               \
    pv.x = f2bf(p0); pv.y = f2bf(p1); pv.z = f2bf(p2); pv.w = f2bf(p3);       \
    dacc += bf2f(pv.x) + bf2f(pv.y) + bf2f(pv.z) + bf2f(pv.w);                \
    *(ushort4*)(pdst) = pv;                                                   \
  }

  // body(it): [stage B(it+1)] [P(it+1)->Pt, reload pair(it+3)] [lgkm+bar]
  // [vmcnt(VMC)] [ds_read frags from buf CUR] [16 MFMA] [bar]
#define BODY(IT_, PA_, PB_, PW_, MKV_, SVV_, NXTB_, DO_P, DO_STAGE, VMC_)     \
  {                                                                           \
    if (DO_STAGE) { STAGE_B(NXTB_, (IT_) + 1); }                              \
    __builtin_amdgcn_sched_barrier(0);                                        \
    if (DO_P) { P_COMP(MKV_, SVV_, PW_); }                                    \
    if (DO_STAGE) {                                                           \
      int kM_ = (((IT_) + 3) & 31) * 32;                                      \
      MKV_ = *(const int4*)(mrow + kM_);                                      \
      SVV_ = *(const float4*)(sptr + kM_);                                    \
    }                                                                         \
    __builtin_amdgcn_sched_barrier(0);                                        \
    asm volatile("s_waitcnt lgkmcnt(0)\n\ts_barrier" ::: "memory");           \
    asm volatile("s_waitcnt vmcnt(" #VMC_ ")" ::: "memory");                  \
    bf16x8 af[4], bfr[4];                                                     \
    _Pragma("unroll") for (int m = 0; m < 4; ++m)                             \
      af[m] = *(const bf16x8*)(PA_ + m * 512);                                \
    _Pragma("unroll") for (int n = 0; n < 4; ++n)                             \
      bfr[n] = *(const bf16x8*)(PB_ + n * 512);                               \
    __builtin_amdgcn_s_setprio(1);                                            \
    _Pragma("unroll") for (int m = 0; m < 4; ++m)                             \
      _Pragma("unroll") for (int n = 0; n < 4; ++n)                           \
        acc[m][n] = __builtin_amdgcn_mfma_f32_16x16x32_bf16(af[m], bfr[n],    \
                                                            acc[m][n], 0, 0, 0); \
    __builtin_amdgcn_s_setprio(0);                                            \
    asm volatile("s_barrier" ::: "memory");                                   \
  }

  // ---- prologue ----
  STAGE_B(&Bt[0][0], 0);
  __builtin_amdgcn_sched_barrier(0);
  {
    int4 mk0 = *(const int4*)(mrow);
    float4 sv0 = *(const float4*)(sptr);
    P_COMP(mk0, sv0, pw0);
  }
  int4 mkA = *(const int4*)(mrow + 32);
  float4 svA = *(const float4*)(sptr + 32);
  int4 mkB = *(const int4*)(mrow + 64);
  float4 svB = *(const float4*)(sptr + 64);
  __builtin_amdgcn_sched_barrier(0);
  asm volatile("s_waitcnt lgkmcnt(0)\n\ts_barrier" ::: "memory");

  // ---- main loop: 32 K-steps, unrolled by 2 ----
  for (int it2 = 0; it2 < 15; ++it2) {
    int it = it2 * 2;
    BODY(it,     pa0, pb0, pw1, mkA, svA, &Bt[1][0], true, true, 8);
    BODY(it + 1, pa1, pb1, pw0, mkB, svB, &Bt[0][0], true, true, 8);
  }
  BODY(30, pa0, pb0, pw1, mkA, svA, &Bt[1][0], true, true, 8);
  BODY(31, pa1, pb1, pw0, mkB, svB, &Bt[0][0], false, false, 2);

  // ---- denominator: 8 threads per row (within one wave) ----
  dacc += __shfl_xor(dacc, 4, 64);
  dacc += __shfl_xor(dacc, 2, 64);
  dacc += __shfl_xor(dacc, 1, 64);
  if ((t & 7) == 0) den[s * 4096 + i0 + i_loc] = dacc;
  // ---- numerator write, packed [s][i>>2][512][i&3] bf16, ushort4/lane ----
#pragma unroll
  for (int m = 0; m < 4; ++m)
#pragma unroll
    for (int n = 0; n < 4; ++n) {
      int ig = rblk * 16 + m * 4 + (l >> 4);   // (i0 + m*16 + (l>>4)*4) / 4
      int f = w * 64 + n * 16 + l15;
      ushort4 o;
      o.x = f2bf(acc[m][n][0]); o.y = f2bf(acc[m][n][1]);
      o.z = f2bf(acc[m][n][2]); o.w = f2bf(acc[m][n][3]);
      *(ushort4*)(num + (((size_t)s * 1024 + ig) * 512 + f) * 4) = o;
    }
#undef BODY
#undef P_COMP
#undef STAGE_B
}

// out[ig*4+r][f] = (sum_s num[s][ig][f][r]) / (sum_s den[s][ig*4+r])
__global__ void reduce_out(const ushort* __restrict__ num, const float* __restrict__ den,
                           float* __restrict__ out) {
  int idx = blockIdx.x * 256 + threadIdx.x;  // 524288 threads
  int ig = idx >> 9, f = idx & 511;
  float s0 = 0.f, s1 = 0.f, s2 = 0.f, s3 = 0.f;
#pragma unroll
  for (int s = 0; s < 8; ++s) {
    ushort4 v = *(const ushort4*)(num + (((size_t)s * 1024 + ig) * 512 + f) * 4);
    s0 += bf2f(v.x); s1 += bf2f(v.y); s2 += bf2f(v.z); s3 += bf2f(v.w);
  }
  float d0 = 0.f, d1 = 0.f, d2 = 0.f, d3 = 0.f;
#pragma unroll
  for (int s = 0; s < 8; ++s) {
    const float* dp = den + s * 4096 + ig * 4;
    d0 += dp[0]; d1 += dp[1]; d2 += dp[2]; d3 += dp[3];
  }
  float* op = out + (size_t)ig * 4 * 512 + f;
  op[0]        = s0 / d0;
  op[512]      = s1 / d1;
  op[2 * 512]  = s2 / d2;
  op[3 * 512]  = s3 / d3;
}

extern "C" void kernel_launch(void* const* d_in, const int* in_sizes, int n_in,
                              void* d_out, int out_size, void* d_ws, size_t ws_size,
                              hipStream_t stream) {
  const float* node   = (const float*)d_in[0];
  const float* neigh  = (const float*)d_in[1];
  const float* weight = (const float*)d_in[2];
  const float* att    = (const float*)d_in[3];
  const int*   mask   = (const int*)d_in[4];
  float* out = (float*)d_out;

  char* ws = (char*)d_ws;
  float* w_a1 = (float*)ws;            // 512
  float* w_a2 = w_a1 + 512;            // 512
  float* s_n  = w_a2 + 512;            // 4096
  float* s_m  = s_n + 4096;            // 8192
  float* smax = s_m + 8192;            // 1
  ushort* neigh_bf = (ushort*)(ws + 64 * 1024);    // 8 MB
  ushort* wT_bf    = neigh_bf + 8192 * 512;        // 0.5 MB
  ushort* WhmT     = wT_bf + 512 * 512;            // 8 MB
  ushort* num      = WhmT + 512 * 8192;            // 32 MB (bf16, packed)
  float*  den      = (float*)(num + (size_t)8 * 1024 * 512 * 4);  // 128 KB

  rowdot<<<128, 256, 0, stream>>>(weight, att, w_a1);
  rowdot<<<128, 256, 0, stream>>>(weight, att + 512, w_a2);
  rowdot<<<1024, 256, 0, stream>>>(node, w_a1, s_n);
  rowdot<<<2048, 256, 0, stream>>>(neigh, w_a2, s_m);
  reduce_max<<<1, 256, 0, stream>>>(s_m, smax);
  cvt4_bf16<<<4096, 256, 0, stream>>>(neigh, neigh_bf);
  transpose_w<<<256, 256, 0, stream>>>(weight, wT_bf);
  gemm_whmT<<<256, 256, 0, stream>>>(neigh_bf, wT_bf, WhmT);
  attn_main<<<512, 512, 0, stream>>>(WhmT, mask, s_n, s_m, smax, num, den);
  reduce_out<<<2048, 256, 0, stream>>>(num, den, out);
}

// Round 6
// 112.816 us; speedup vs baseline: 2.0814x; 1.8695x over previous
//
#include <hip/hip_runtime.h>
#include <stdint.h>

#define LOG2E 1.44269504088896340736f

using bf16x8 = __attribute__((ext_vector_type(8))) short;  // 8 bf16 (4 VGPRs)
using f32x4  = __attribute__((ext_vector_type(4))) float;

__device__ __forceinline__ ushort f2bf(float f) {
  union { float f; uint32_t u; } v; v.f = f;
  uint32_t u = v.u;
  u += 0x7FFFu + ((u >> 16) & 1u);   // RNE
  return (ushort)(u >> 16);
}
__device__ __forceinline__ float bf2f(ushort b) {
  union { uint32_t u; float f; } v; v.u = ((uint32_t)b) << 16;
  return v.f;
}

__device__ __forceinline__ void load_lds16(const void* g, void* l) {
  __builtin_amdgcn_global_load_lds(
      (const __attribute__((address_space(1))) void*)g,
      (__attribute__((address_space(3))) void*)l, 16, 0, 0);
}

// out[row] = dot(mat[row, 0:512], vec[0:512]); 4 rows per 256-thread block
__global__ void rowdot(const float* __restrict__ mat, const float* __restrict__ vec,
                       float* __restrict__ out) {
  int w = threadIdx.x >> 6, l = threadIdx.x & 63;
  int row = blockIdx.x * 4 + w;
  const float4* mp = (const float4*)(mat + row * 512 + l * 8);
  const float4* vp = (const float4*)(vec + l * 8);
  float4 a0 = mp[0], a1 = mp[1];
  float4 b0 = vp[0], b1 = vp[1];
  float d = a0.x * b0.x + a0.y * b0.y + a0.z * b0.z + a0.w * b0.w
          + a1.x * b1.x + a1.y * b1.y + a1.z * b1.z + a1.w * b1.w;
#pragma unroll
  for (int o = 32; o > 0; o >>= 1) d += __shfl_xor(d, o, 64);
  if (l == 0) out[row] = d;
}

__global__ void reduce_max(const float* __restrict__ v, float* __restrict__ outmax) {
  __shared__ float red[4];
  int t = threadIdx.x;
  float m = -3.0e38f;
  for (int j = t; j < 8192; j += 256) m = fmaxf(m, v[j]);
#pragma unroll
  for (int o = 32; o > 0; o >>= 1) m = fmaxf(m, __shfl_xor(m, o, 64));
  if ((t & 63) == 0) red[t >> 6] = m;
  __syncthreads();
  if (t == 0) outmax[0] = fmaxf(fmaxf(red[0], red[1]), fmaxf(red[2], red[3]));
}

__global__ void cvt4_bf16(const float* __restrict__ in, ushort* __restrict__ out) {
  int idx = blockIdx.x * 256 + threadIdx.x;
  float4 v = ((const float4*)in)[idx];
  ushort4 o; o.x = f2bf(v.x); o.y = f2bf(v.y); o.z = f2bf(v.z); o.w = f2bf(v.w);
  ((ushort4*)out)[idx] = o;
}

// wT_bf[f][c] = bf16(weight[c][f]); 512x512
__global__ void transpose_w(const float* __restrict__ w, ushort* __restrict__ wT) {
  __shared__ float tile[32][33];
  int t = threadIdx.x; int tx = t & 31, ty = t >> 5;
  int cb = (blockIdx.x & 15) * 32, fb = (blockIdx.x >> 4) * 32;
#pragma unroll
  for (int k = 0; k < 4; ++k) tile[ty + k * 8][tx] = w[(cb + ty + k * 8) * 512 + fb + tx];
  __syncthreads();
#pragma unroll
  for (int k = 0; k < 4; ++k) wT[(fb + ty + k * 8) * 512 + cb + tx] = f2bf(tile[tx][ty + k * 8]);
}

// WhmT[f][j] = sum_c neigh_bf[j][c] * wT_bf[f][c]   (bf16 out, transposed store)
__global__ __launch_bounds__(256, 4) void gemm_whmT(const ushort* __restrict__ A,
                                                    const ushort* __restrict__ B,
                                                    ushort* __restrict__ WhmT) {
  __shared__ ushort At[128 * 32];
  __shared__ ushort Bt2[128 * 32];
  int t = threadIdx.x;
  int j0 = (blockIdx.x >> 2) * 128, f0 = (blockIdx.x & 3) * 128;
  int w = t >> 6, l = t & 63, wr = w >> 1, wc = w & 1;
  f32x4 acc[4][4] = {};
  for (int it = 0; it < 16; ++it) {
    int k0 = it * 32;
#pragma unroll
    for (int c = 0; c < 2; ++c) {
      int u = c * 256 + t; int rr = u >> 2, p = u & 3;
      int sg = p ^ ((rr >> 1) & 3);
      load_lds16(A + (j0 + rr) * 512 + k0 + sg * 8, At + (c * 256 + (t & ~63)) * 8);
      load_lds16(B + (f0 + rr) * 512 + k0 + sg * 8, Bt2 + (c * 256 + (t & ~63)) * 8);
    }
    __syncthreads();
    bf16x8 af[4], bfr[4];
#pragma unroll
    for (int m = 0; m < 4; ++m) {
      int rr = wr * 64 + m * 16 + (l & 15);
      int q = (l >> 4) ^ ((rr >> 1) & 3);
      af[m] = *(const bf16x8*)(At + rr * 32 + q * 8);
    }
#pragma unroll
    for (int n = 0; n < 4; ++n) {
      int rb = wc * 64 + n * 16 + (l & 15);
      int q = (l >> 4) ^ ((rb >> 1) & 3);
      bfr[n] = *(const bf16x8*)(Bt2 + rb * 32 + q * 8);
    }
#pragma unroll
    for (int m = 0; m < 4; ++m)
#pragma unroll
      for (int n = 0; n < 4; ++n)
        acc[m][n] = __builtin_amdgcn_mfma_f32_16x16x32_bf16(af[m], bfr[n], acc[m][n], 0, 0, 0);
    __syncthreads();
  }
#pragma unroll
  for (int m = 0; m < 4; ++m)
#pragma unroll
    for (int n = 0; n < 4; ++n) {
      int j = j0 + wr * 64 + m * 16 + (l >> 4) * 4;
      int f = f0 + wc * 64 + n * 16 + (l & 15);
      ushort4 o;
      o.x = f2bf(acc[m][n][0]); o.y = f2bf(acc[m][n][1]);
      o.z = f2bf(acc[m][n][2]); o.w = f2bf(acc[m][n][3]);
      *(ushort4*)(WhmT + f * 8192 + j) = o;
    }
}

// ---------------------------------------------------------------------------
// Main fused kernel v6: BM=64, BN=512, BK=32, Ksplit=8 -> grid 512 (2 blk/CU).
// Register-lean: single mk/sv pair set (consume-then-reissue, 1-body flight),
// per-n bfr loads, no explicit vmcnt (compiler's counted pair-wait retires the
// previous stage before the barrier -> counted pipeline, never vmcnt(0)).
// Numerator packed: num[s][i>>2][f][i&3] bf16 -> 128B full-line stores.
// ---------------------------------------------------------------------------
__global__ __launch_bounds__(512, 4) void attn_main(
    const ushort* __restrict__ WhmT, const int* __restrict__ mask,
    const float* __restrict__ s_n, const float* __restrict__ s_m,
    const float* __restrict__ smaxp, ushort* __restrict__ num, float* __restrict__ den) {
  __shared__ ushort Bt[2][512 * 32];  // 2 x 32 KB, xor-swizzled [f][32j]
  __shared__ ushort Pt[2][64 * 32];   // 2 x 4 KB, xor-swizzled [i][32j]
  int t = threadIdx.x;
  int bid = blockIdx.x;
  int s = bid & 7;           // ksplit == XCD id under round-robin dispatch
  int rblk = bid >> 3;       // 0..63
  int i0 = rblk * 64;
  int kb = s * 1024;
  int w = t >> 6, l = t & 63, l15 = l & 15;
  int i_loc = t >> 3, jt = t & 7;

  float sn = s_n[i0 + i_loc];
  float smx = smaxp[0];
  float mz = sn + smx;
  float m_i = mz > 0.f ? mz : 0.2f * mz;
  float miL = m_i * LOG2E;
  float dacc = 0.f;
  f32x4 acc[4][4] = {};

  // P write addrs (4 bf16 per thread, xor-swizzled 16B groups)
  int psP = (jt >> 1) ^ ((i_loc >> 1) & 3);
  ushort* pw0 = &Pt[0][0] + i_loc * 32 + psP * 8 + (jt & 1) * 4;
  ushort* pw1 = &Pt[1][0] + i_loc * 32 + psP * 8 + (jt & 1) * 4;
  // frag read bases (swizzle group independent of m/n since 16|row steps)
  int qA = (l >> 4) ^ ((l15 >> 1) & 3);
  const ushort* pa0 = &Pt[0][0] + l15 * 32 + qA * 8;
  const ushort* pa1 = &Pt[1][0] + l15 * 32 + qA * 8;
  const ushort* pb0 = &Bt[0][0] + (w * 64 + l15) * 32 + qA * 8;
  const ushort* pb1 = &Bt[1][0] + (w * 64 + l15) * 32 + qA * 8;

  const int* mrow = mask + (size_t)(i0 + i_loc) * 8192 + kb + jt * 4;
  const float* sptr = s_m + kb + jt * 4;

#define STAGE_B(BUF_, T_)                                                     \
  {                                                                           \
    int k0_ = kb + (T_) * 32;                                                 \
    ushort* bb_ = BUF_;                                                       \
    _Pragma("unroll") for (int c = 0; c < 4; ++c) {                           \
      int u_ = c * 512 + t; int rr_ = u_ >> 2, p_ = u_ & 3;                   \
      int sg_ = p_ ^ ((rr_ >> 1) & 3);                                        \
      load_lds16(WhmT + rr_ * 8192 + k0_ + sg_ * 8,                           \
                 bb_ + (c * 512 + (t & ~63)) * 8);                            \
    }                                                                         \
  }

#define P_COMP(mkv, svv, pdst)                                                \
  {                                                                           \
    float z0 = sn + (svv).x, z1 = sn + (svv).y;                               \
    float z2 = sn + (svv).z, z3 = sn + (svv).w;                               \
    float e0 = (z0 > 0.f ? z0 : 0.2f * z0) * LOG2E - miL;                     \
    float e1 = (z1 > 0.f ? z1 : 0.2f * z1) * LOG2E - miL;                     \
    float e2 = (z2 > 0.f ? z2 : 0.2f * z2) * LOG2E - miL;                     \
    float e3 = (z3 > 0.f ? z3 : 0.2f * z3) * LOG2E - miL;                     \
    float p0 = (mkv).x > 0 ? exp2f(e0) : 0.f;                                 \
    float p1 = (mkv).y > 0 ? exp2f(e1) : 0.f;                                 \
    float p2 = (mkv).z > 0 ? exp2f(e2) : 0.f;                                 \
    float p3 = (mkv).w > 0 ? exp2f(e3) : 0.f;                                 \
    ushort4 pv;                                                               \
    pv.x = f2bf(p0); pv.y = f2bf(p1); pv.z = f2bf(p2); pv.w = f2bf(p3);       \
    dacc += bf2f(pv.x) + bf2f(pv.y) + bf2f(pv.z) + bf2f(pv.w);                \
    *(ushort4*)(pdst) = pv;                                                   \
  }

  // BODY(it): stage B(it+1); P(it+1) from flying pair (compiler inserts a
  // COUNTED vmcnt here, which also retires stage(it)); reissue pair(it+2);
  // lgkm+barrier; frags from Bt/Pt[cur]; 16 MFMA; barrier.
#define BODY(IT_, PA_, PB_, PW_, DO_P, DO_STAGE)                              \
  {                                                                           \
    if (DO_STAGE) { STAGE_B((((IT_) & 1) ? &Bt[0][0] : &Bt[1][0]), (IT_) + 1); } \
    if (DO_P) { P_COMP(mkR, svR, PW_); }                                      \
    if (DO_STAGE) {                                                           \
      int kM_ = (((IT_) + 2) & 31) * 32;                                      \
      mkR = *(const int4*)(mrow + kM_);                                       \
      svR = *(const float4*)(sptr + kM_);                                     \
    }                                                                         \
    __builtin_amdgcn_sched_barrier(0);                                        \
    asm volatile("s_waitcnt lgkmcnt(0)\n\ts_barrier" ::: "memory");           \
    __builtin_amdgcn_sched_barrier(0);                                        \
    bf16x8 af[4];                                                             \
    _Pragma("unroll") for (int m = 0; m < 4; ++m)                             \
      af[m] = *(const bf16x8*)(PA_ + m * 512);                                \
    __builtin_amdgcn_s_setprio(1);                                            \
    _Pragma("unroll") for (int n = 0; n < 4; ++n) {                           \
      bf16x8 bfr = *(const bf16x8*)(PB_ + n * 512);                           \
      _Pragma("unroll") for (int m = 0; m < 4; ++m)                           \
        acc[m][n] = __builtin_amdgcn_mfma_f32_16x16x32_bf16(af[m], bfr,       \
                                                            acc[m][n], 0, 0, 0); \
    }                                                                         \
    __builtin_amdgcn_s_setprio(0);                                            \
    asm volatile("s_barrier" ::: "memory");                                   \
  }

  // ---- prologue: stage(0); P(0) direct; issue pair(1); barrier ----
  STAGE_B(&Bt[0][0], 0);
  int4 mkR; float4 svR;
  {
    int4 mk0 = *(const int4*)(mrow);
    float4 sv0 = *(const float4*)(sptr);
    P_COMP(mk0, sv0, pw0);
  }
  mkR = *(const int4*)(mrow + 32);
  svR = *(const float4*)(sptr + 32);
  __builtin_amdgcn_sched_barrier(0);
  asm volatile("s_waitcnt lgkmcnt(0)\n\ts_barrier" ::: "memory");
  __builtin_amdgcn_sched_barrier(0);

  // ---- main loop: 32 K-steps, unrolled by 2 ----
  for (int it2 = 0; it2 < 15; ++it2) {
    int it = it2 * 2;
    BODY(it,     pa0, pb0, pw1, true, true);
    BODY(it + 1, pa1, pb1, pw0, true, true);
  }
  BODY(30, pa0, pb0, pw1, true, true);
  BODY(31, pa1, pb1, pw0, false, false);

  // ---- denominator: 8 threads per row (within one wave) ----
  dacc += __shfl_xor(dacc, 4, 64);
  dacc += __shfl_xor(dacc, 2, 64);
  dacc += __shfl_xor(dacc, 1, 64);
  if ((t & 7) == 0) den[s * 4096 + i0 + i_loc] = dacc;
  // ---- numerator write, packed [s][i>>2][512][i&3] bf16, ushort4/lane ----
#pragma unroll
  for (int m = 0; m < 4; ++m)
#pragma unroll
    for (int n = 0; n < 4; ++n) {
      int ig = rblk * 16 + m * 4 + (l >> 4);   // (i0 + m*16 + (l>>4)*4) / 4
      int f = w * 64 + n * 16 + l15;
      ushort4 o;
      o.x = f2bf(acc[m][n][0]); o.y = f2bf(acc[m][n][1]);
      o.z = f2bf(acc[m][n][2]); o.w = f2bf(acc[m][n][3]);
      *(ushort4*)(num + (((size_t)s * 1024 + ig) * 512 + f) * 4) = o;
    }
#undef BODY
#undef P_COMP
#undef STAGE_B
}

// out[ig*4+r][f] = (sum_s num[s][ig][f][r]) / (sum_s den[s][ig*4+r])
__global__ void reduce_out(const ushort* __restrict__ num, const float* __restrict__ den,
                           float* __restrict__ out) {
  int idx = blockIdx.x * 256 + threadIdx.x;  // 524288 threads
  int ig = idx >> 9, f = idx & 511;
  float s0 = 0.f, s1 = 0.f, s2 = 0.f, s3 = 0.f;
#pragma unroll
  for (int s = 0; s < 8; ++s) {
    ushort4 v = *(const ushort4*)(num + (((size_t)s * 1024 + ig) * 512 + f) * 4);
    s0 += bf2f(v.x); s1 += bf2f(v.y); s2 += bf2f(v.z); s3 += bf2f(v.w);
  }
  float d0 = 0.f, d1 = 0.f, d2 = 0.f, d3 = 0.f;
#pragma unroll
  for (int s = 0; s < 8; ++s) {
    const float* dp = den + s * 4096 + ig * 4;
    d0 += dp[0]; d1 += dp[1]; d2 += dp[2]; d3 += dp[3];
  }
  float* op = out + (size_t)ig * 4 * 512 + f;
  op[0]        = s0 / d0;
  op[512]      = s1 / d1;
  op[2 * 512]  = s2 / d2;
  op[3 * 512]  = s3 / d3;
}

extern "C" void kernel_launch(void* const* d_in, const int* in_sizes, int n_in,
                              void* d_out, int out_size, void* d_ws, size_t ws_size,
                              hipStream_t stream) {
  const float* node   = (const float*)d_in[0];
  const float* neigh  = (const float*)d_in[1];
  const float* weight = (const float*)d_in[2];
  const float* att    = (const float*)d_in[3];
  const int*   mask   = (const int*)d_in[4];
  float* out = (float*)d_out;

  char* ws = (char*)d_ws;
  float* w_a1 = (float*)ws;            // 512
  float* w_a2 = w_a1 + 512;            // 512
  float* s_n  = w_a2 + 512;            // 4096
  float* s_m  = s_n + 4096;            // 8192
  float* smax = s_m + 8192;            // 1
  ushort* neigh_bf = (ushort*)(ws + 64 * 1024);    // 8 MB
  ushort* wT_bf    = neigh_bf + 8192 * 512;        // 0.5 MB
  ushort* WhmT     = wT_bf + 512 * 512;            // 8 MB
  ushort* num      = WhmT + 512 * 8192;            // 32 MB (bf16, packed)
  float*  den      = (float*)(num + (size_t)8 * 1024 * 512 * 4);  // 128 KB

  rowdot<<<128, 256, 0, stream>>>(weight, att, w_a1);
  rowdot<<<128, 256, 0, stream>>>(weight, att + 512, w_a2);
  rowdot<<<1024, 256, 0, stream>>>(node, w_a1, s_n);
  rowdot<<<2048, 256, 0, stream>>>(neigh, w_a2, s_m);
  reduce_max<<<1, 256, 0, stream>>>(s_m, smax);
  cvt4_bf16<<<4096, 256, 0, stream>>>(neigh, neigh_bf);
  transpose_w<<<256, 256, 0, stream>>>(weight, wT_bf);
  gemm_whmT<<<256, 256, 0, stream>>>(neigh_bf, wT_bf, WhmT);
  attn_main<<<512, 512, 0, stream>>>(WhmT, mask, s_n, s_m, smax, num, den);
  reduce_out<<<2048, 256, 0, stream>>>(num, den, out);
}